// Round 5
// baseline (137.239 us; speedup 1.0000x reference)
//
#include <hip/hip_runtime.h>
#include <stdint.h>

#define INF    4096
#define OUTF   11008
#define NTOK   256
#define QZ_COLS (OUTF / 8)   // 1376
#define NTILES  (INF / 128)  // 32 K-tiles, one quant group each

#define BM 64
#define BN 128

typedef __attribute__((ext_vector_type(8))) _Float16 f16x8;
typedef __attribute__((ext_vector_type(2))) _Float16 f16x2;
typedef __attribute__((ext_vector_type(4))) float    f32x4;

static_assert(sizeof(f16x8) == 16, "f16x8 must be 16B");

__global__ __launch_bounds__(256, 2)
void qlin_mfma(const float* __restrict__ x,
               const float* __restrict__ scales,
               const float* __restrict__ bias,
               const int*   __restrict__ qweight,
               const int*   __restrict__ qzeros,
               float*       __restrict__ out)
{
    // [k8][row][4 dwords = 8 f16], k within a dword-quad is interleaved (j, j+4)
    __shared__ uint32_t A_sh[16][BM][4];   // 16 KiB
    __shared__ uint32_t B_sh[16][BN][4];   // 32 KiB

    const int tid = threadIdx.x;
    const int n0  = blockIdx.x * BN;   // 0..85
    const int m0  = blockIdx.y * BM;   // 0..3

    const int lane = tid & 63;
    const int wid  = tid >> 6;
    const int wm   = wid >> 1;   // 0..1 : 32-row slab
    const int wn   = wid & 1;    // 0..1 : 64-col slab
    const int l15  = lane & 15;
    const int l4   = lane >> 4;  // 0..3

    float acc[2][4][4];
    f32x4 accg[2][4];
    #pragma unroll
    for (int i = 0; i < 2; ++i)
        #pragma unroll
        for (int j = 0; j < 4; ++j) {
            accg[i][j] = f32x4{0.f, 0.f, 0.f, 0.f};
            #pragma unroll
            for (int r = 0; r < 4; ++r) acc[i][j][r] = 0.f;
        }

    // B staging: idx = r*256+tid -> oL = tid&127 (fixed per thread), k8 = 2r + (tid>>7)
    const int oL  = tid & 127;
    const int thi = tid >> 7;
    const int zsh = (oL & 7) * 4;
    const int zwordIdx = (n0 + oL) >> 3;

    // A staging: idx = r*256+tid -> kc = tid&15, m = (tid>>4) + 16r  (coalesced 512B rows)
    const int a_kc = tid & 15;
    const int a_m  = tid >> 4;

    for (int t = 0; t < NTILES; ++t) {
        // ---- prefetch per-group scalars (global, L2-resident) ----
        float sj[4];
        #pragma unroll
        for (int j = 0; j < 4; ++j)
            sj[j] = scales[t * OUTF + n0 + wn * 64 + j * 16 + l15];

        const int zw = qzeros[t * QZ_COLS + zwordIdx];
        const int z  = ((zw >> zsh) & 15) + 1;
        const _Float16 hz = (_Float16)(float)(1024 + z);
        const f16x2 z2 = {hz, hz};

        // ---- stage A: x[m0+m, 128t .. +128) -> f16, k-permuted (p, p+4) pairs ----
        #pragma unroll
        for (int r = 0; r < 4; ++r) {
            const int m = a_m + r * 16;
            const float* src = x + (size_t)(m0 + m) * INF + t * 128 + a_kc * 8;
            const f32x4 v0 = *(const f32x4*)src;        // k offsets 0..3
            const f32x4 v1 = *(const f32x4*)(src + 4);  // k offsets 4..7
            uint32_t d[4];
            #pragma unroll
            for (int p = 0; p < 4; ++p)
                d[p] = __builtin_bit_cast(uint32_t,
                          __builtin_amdgcn_cvt_pkrtz(v0[p], v1[p])); // (lo=k p, hi=k p+4)
            *(uint4*)&A_sh[a_kc][(m) ^ (a_kc & 7)][0] = make_uint4(d[0], d[1], d[2], d[3]);
        }

        // ---- stage B: unpack 8 int4 per word via fp16 magic, zero folded in ----
        #pragma unroll
        for (int r = 0; r < 8; ++r) {
            const int k8 = r * 2 + thi;
            const uint32_t w = (uint32_t)qweight[(size_t)(t * 16 + k8) * OUTF + n0 + oL];
            uint32_t d[4];
            #pragma unroll
            for (int p = 0; p < 4; ++p) {
                const uint32_t bv = ((w >> (4 * p)) & 0x000F000Fu) | 0x64006400u;
                const f16x2 hv = __builtin_bit_cast(f16x2, bv) - z2; // exact (q - z)
                d[p] = __builtin_bit_cast(uint32_t, hv);
            }
            *(uint4*)&B_sh[k8][oL][0] = make_uint4(d[0], d[1], d[2], d[3]);
        }

        __syncthreads();

        // ---- compute: 4 k-steps of 32, 8 MFMA each ----
        #pragma unroll
        for (int kk = 0; kk < 4; ++kk) {
            const int k8 = kk * 4 + l4;
            f16x8 a[2], b[4];
            #pragma unroll
            for (int i = 0; i < 2; ++i)
                a[i] = *(const f16x8*)&A_sh[k8][(wm * 32 + i * 16 + l15) ^ (k8 & 7)][0];
            #pragma unroll
            for (int j = 0; j < 4; ++j)
                b[j] = *(const f16x8*)&B_sh[k8][wn * 64 + j * 16 + l15][0];
            #pragma unroll
            for (int i = 0; i < 2; ++i)
                #pragma unroll
                for (int j = 0; j < 4; ++j)
                    accg[i][j] = __builtin_amdgcn_mfma_f32_16x16x32_f16(
                                     a[i], b[j], accg[i][j], 0, 0, 0);
        }

        // ---- fold group into running accumulator with per-(g,col) scale ----
        #pragma unroll
        for (int j = 0; j < 4; ++j)
            #pragma unroll
            for (int i = 0; i < 2; ++i) {
                #pragma unroll
                for (int r = 0; r < 4; ++r) {
                    acc[i][j][r] += sj[j] * accg[i][j][r];
                }
                accg[i][j] = f32x4{0.f, 0.f, 0.f, 0.f};
            }

        __syncthreads();
    }

    // ---- epilogue: C[row][col] = acc + bias, row=(lane>>4)*4+reg, col=lane&15 ----
    #pragma unroll
    for (int j = 0; j < 4; ++j) {
        const int col = n0 + wn * 64 + j * 16 + l15;
        const float bv = bias[col];
        #pragma unroll
        for (int i = 0; i < 2; ++i) {
            const int row0 = m0 + wm * 32 + i * 16 + l4 * 4;
            #pragma unroll
            for (int r = 0; r < 4; ++r)
                out[(size_t)(row0 + r) * OUTF + col] = acc[i][j][r] + bv;
        }
    }
}

extern "C" void kernel_launch(void* const* d_in, const int* in_sizes, int n_in,
                              void* d_out, int out_size, void* d_ws, size_t ws_size,
                              hipStream_t stream)
{
    const float* x       = (const float*)d_in[0];
    const float* scales  = (const float*)d_in[1];
    const float* bias    = (const float*)d_in[2];
    const int*   qweight = (const int*)d_in[3];
    const int*   qzeros  = (const int*)d_in[4];
    // d_in[5] = g_idx : deterministic (i // 128), not needed on device
    float* out = (float*)d_out;

    dim3 grid(OUTF / BN, NTOK / BM);  // (86, 4) = 344 blocks
    qlin_mfma<<<grid, dim3(256), 0, stream>>>(x, scales, bias, qweight, qzeros, out);
}

// Round 7
// 133.900 us; speedup vs baseline: 1.0249x; 1.0249x over previous
//
#include <hip/hip_runtime.h>
#include <stdint.h>

#define INF    4096
#define OUTF   11008
#define NTOK   256
#define QZ_COLS (OUTF / 8)   // 1376
#define NTILES  (INF / 128)  // 32 K-tiles, one quant group each

#define BM 64
#define BN 64

typedef __attribute__((ext_vector_type(8))) _Float16 f16x8;
typedef __attribute__((ext_vector_type(2))) _Float16 f16x2;
typedef __attribute__((ext_vector_type(4))) float    f32x4;

static_assert(sizeof(f16x8) == 16, "f16x8 must be 16B");

__global__ __launch_bounds__(256, 2)
void qlin_mfma(const float* __restrict__ x,
               const float* __restrict__ scales,
               const float* __restrict__ bias,
               const int*   __restrict__ qweight,
               const int*   __restrict__ qzeros,
               float*       __restrict__ out)
{
    // [k8][row][4 dwords = 8 f16], k within a dword-quad is interleaved (j, j+4)
    __shared__ uint32_t A_sh[16][BM][4];   // 16 KiB
    __shared__ uint32_t B_sh[16][BN][4];   // 16 KiB

    const int tid = threadIdx.x;
    const int n0  = blockIdx.x * BN;   // 0..171
    const int m0  = blockIdx.y * BM;   // 0..3

    const int lane = tid & 63;
    const int wid  = tid >> 6;
    const int wm   = wid >> 1;   // 0..1 : 32-row slab
    const int wn   = wid & 1;    // 0..1 : 32-col slab
    const int l15  = lane & 15;
    const int l4   = lane >> 4;  // 0..3

    float acc[2][2][4];
    f32x4 accg[2][2];
    #pragma unroll
    for (int i = 0; i < 2; ++i)
        #pragma unroll
        for (int j = 0; j < 2; ++j) {
            accg[i][j] = f32x4{0.f, 0.f, 0.f, 0.f};
            #pragma unroll
            for (int r = 0; r < 4; ++r) acc[i][j][r] = 0.f;
        }

    // B staging: 16x64 words; thread covers oL = tid&63 (wave-contiguous 256B),
    // k8 = 4r + (tid>>6)
    const int oL  = tid & 63;
    const int thi = tid >> 6;   // 0..3
    const int zsh = (oL & 7) * 4;
    const int zwordIdx = (n0 + oL) >> 3;

    // A staging: kc = tid&15, m = (tid>>4) + 16r  (coalesced 512B rows)
    const int a_kc = tid & 15;
    const int a_m  = tid >> 4;

    for (int t = 0; t < NTILES; ++t) {
        // ---- per-group scalars (L2/L3-resident) ----
        float sj[2];
        #pragma unroll
        for (int j = 0; j < 2; ++j)
            sj[j] = scales[t * OUTF + n0 + wn * 32 + j * 16 + l15];

        const int zw = qzeros[t * QZ_COLS + zwordIdx];
        const int z  = ((zw >> zsh) & 15) + 1;
        const _Float16 hz = (_Float16)(float)(1024 + z);
        const f16x2 z2 = {hz, hz};

        // ---- stage A: x[m0+m, 128t .. +128) -> f16, k-permuted (p, p+4) pairs ----
        #pragma unroll
        for (int r = 0; r < 4; ++r) {
            const int m = a_m + r * 16;
            const float* src = x + (size_t)(m0 + m) * INF + t * 128 + a_kc * 8;
            const f32x4 v0 = *(const f32x4*)src;        // k offsets 0..3
            const f32x4 v1 = *(const f32x4*)(src + 4);  // k offsets 4..7
            uint32_t d[4];
            #pragma unroll
            for (int p = 0; p < 4; ++p)
                d[p] = __builtin_bit_cast(uint32_t,
                          __builtin_amdgcn_cvt_pkrtz(v0[p], v1[p])); // (lo=k p, hi=k p+4)
            *(uint4*)&A_sh[a_kc][(m) ^ (a_kc & 7)][0] = make_uint4(d[0], d[1], d[2], d[3]);
        }

        // ---- stage B: unpack 4 words/thread via fp16 magic, zero folded in ----
        #pragma unroll
        for (int r = 0; r < 4; ++r) {
            const int k8 = r * 4 + thi;
            const uint32_t w = (uint32_t)qweight[(size_t)(t * 16 + k8) * OUTF + n0 + oL];
            uint32_t d[4];
            #pragma unroll
            for (int p = 0; p < 4; ++p) {
                const uint32_t bv = ((w >> (4 * p)) & 0x000F000Fu) | 0x64006400u;
                const f16x2 hv = __builtin_bit_cast(f16x2, bv) - z2; // exact (q - z)
                d[p] = __builtin_bit_cast(uint32_t, hv);
            }
            *(uint4*)&B_sh[k8][oL][0] = make_uint4(d[0], d[1], d[2], d[3]);
        }

        __syncthreads();

        // ---- compute: 4 k-steps of 32, 4 MFMA each ----
        #pragma unroll
        for (int kk = 0; kk < 4; ++kk) {
            const int k8 = kk * 4 + l4;
            f16x8 a[2], b[2];
            #pragma unroll
            for (int i = 0; i < 2; ++i)
                a[i] = *(const f16x8*)&A_sh[k8][(wm * 32 + i * 16 + l15) ^ (k8 & 7)][0];
            #pragma unroll
            for (int j = 0; j < 2; ++j)
                b[j] = *(const f16x8*)&B_sh[k8][wn * 32 + j * 16 + l15][0];
            #pragma unroll
            for (int i = 0; i < 2; ++i)
                #pragma unroll
                for (int j = 0; j < 2; ++j)
                    accg[i][j] = __builtin_amdgcn_mfma_f32_16x16x32_f16(
                                     a[i], b[j], accg[i][j], 0, 0, 0);
        }

        // ---- fold group into running accumulator with per-(g,col) scale ----
        #pragma unroll
        for (int j = 0; j < 2; ++j)
            #pragma unroll
            for (int i = 0; i < 2; ++i) {
                #pragma unroll
                for (int r = 0; r < 4; ++r) {
                    acc[i][j][r] += sj[j] * accg[i][j][r];
                }
                accg[i][j] = f32x4{0.f, 0.f, 0.f, 0.f};
            }

        __syncthreads();
    }

    // ---- epilogue: C[row][col] = acc + bias, row=(lane>>4)*4+reg, col=lane&15 ----
    #pragma unroll
    for (int j = 0; j < 2; ++j) {
        const int col = n0 + wn * 32 + j * 16 + l15;
        const float bv = bias[col];
        #pragma unroll
        for (int i = 0; i < 2; ++i) {
            const int row0 = m0 + wm * 32 + i * 16 + l4 * 4;
            #pragma unroll
            for (int r = 0; r < 4; ++r)
                out[(size_t)(row0 + r) * OUTF + col] = acc[i][j][r] + bv;
        }
    }
}

extern "C" void kernel_launch(void* const* d_in, const int* in_sizes, int n_in,
                              void* d_out, int out_size, void* d_ws, size_t ws_size,
                              hipStream_t stream)
{
    const float* x       = (const float*)d_in[0];
    const float* scales  = (const float*)d_in[1];
    const float* bias    = (const float*)d_in[2];
    const int*   qweight = (const int*)d_in[3];
    const int*   qzeros  = (const int*)d_in[4];
    // d_in[5] = g_idx : deterministic (i // 128), not needed on device
    float* out = (float*)d_out;

    dim3 grid(OUTF / BN, NTOK / BM);  // (172, 4) = 688 blocks, ~2.7/CU
    qlin_mfma<<<grid, dim3(256), 0, stream>>>(x, scales, bias, qweight, qzeros, out);
}

// Round 8
// 127.406 us; speedup vs baseline: 1.0772x; 1.0510x over previous
//
#include <hip/hip_runtime.h>
#include <stdint.h>

#define INF    4096
#define OUTF   11008
#define NTOK   256
#define QZ_COLS (OUTF / 8)   // 1376
#define NTILES  (INF / 128)  // 32 K-tiles, one quant group each

#define BM 64
#define BN 64

typedef __attribute__((ext_vector_type(8))) _Float16 f16x8;
typedef __attribute__((ext_vector_type(2))) _Float16 f16x2;
typedef __attribute__((ext_vector_type(4))) float    f32x4;

static_assert(sizeof(f16x8) == 16, "f16x8 must be 16B");

__global__ __launch_bounds__(256, 2)
void qlin_mfma(const float* __restrict__ x,
               const float* __restrict__ scales,
               const float* __restrict__ bias,
               const int*   __restrict__ qweight,
               const int*   __restrict__ qzeros,
               float*       __restrict__ out)
{
    // [k8][row][4 dwords = 8 f16], k within a dword-quad is interleaved (j, j+4)
    __shared__ uint32_t A_sh[16][BM][4];   // 16 KiB
    __shared__ uint32_t B_sh[16][BN][4];   // 16 KiB

    const int tid = threadIdx.x;
    const int n0  = blockIdx.x * BN;
    const int m0  = blockIdx.y * BM;

    const int lane = tid & 63;
    const int wid  = tid >> 6;
    const int wm   = wid >> 1;   // 0..1 : 32-row slab
    const int wn   = wid & 1;    // 0..1 : 32-col slab
    const int l15  = lane & 15;
    const int l4   = lane >> 4;  // 0..3

    float acc[2][2][4];
    f32x4 accg[2][2];
    #pragma unroll
    for (int i = 0; i < 2; ++i)
        #pragma unroll
        for (int j = 0; j < 2; ++j) {
            accg[i][j] = f32x4{0.f, 0.f, 0.f, 0.f};
            #pragma unroll
            for (int r = 0; r < 4; ++r) acc[i][j][r] = 0.f;
        }

    // B staging: oL = tid&63 (wave-contiguous 256B), k8 = 4r + (tid>>6)
    const int oL  = tid & 63;
    const int thi = tid >> 6;   // 0..3
    const int zsh = (oL & 7) * 4;
    const int zwordIdx = (n0 + oL) >> 3;

    // A staging: kc = tid&15, m = (tid>>4) + 16r  (coalesced 512B rows)
    const int a_kc = tid & 15;
    const int a_m  = tid >> 4;

    // ---- prefetch register set (one K-tile of raw data) ----
    f32x4    pv0[4], pv1[4];   // A: 32 VGPR
    uint32_t pw[4];            // B words
    int      pzw;              // zeros word
    float    psj0, psj1;       // scales

    auto issue = [&](int t) {
        #pragma unroll
        for (int r = 0; r < 4; ++r) {
            const float* src = x + (size_t)(m0 + a_m + r * 16) * INF + t * 128 + a_kc * 8;
            pv0[r] = *(const f32x4*)src;
            pv1[r] = *(const f32x4*)(src + 4);
        }
        #pragma unroll
        for (int r = 0; r < 4; ++r)
            pw[r] = (uint32_t)qweight[(size_t)(t * 16 + r * 4 + thi) * OUTF + n0 + oL];
        pzw  = qzeros[t * QZ_COLS + zwordIdx];
        psj0 = scales[t * OUTF + n0 + wn * 32 + l15];
        psj1 = scales[t * OUTF + n0 + wn * 32 + 16 + l15];
    };

    issue(0);

    for (int t = 0; t < NTILES; ++t) {
        // ---- consume prefetched regs: dequant + LDS stage ----
        const int z = ((pzw >> zsh) & 15) + 1;
        const _Float16 hz = (_Float16)(float)(1024 + z);
        const f16x2 z2 = {hz, hz};
        const float sjf0 = psj0, sjf1 = psj1;   // copy before regs are reissued

        #pragma unroll
        for (int r = 0; r < 4; ++r) {
            uint32_t d[4];
            #pragma unroll
            for (int p = 0; p < 4; ++p)
                d[p] = __builtin_bit_cast(uint32_t,
                          __builtin_amdgcn_cvt_pkrtz(pv0[r][p], pv1[r][p]));
            *(uint4*)&A_sh[a_kc][(a_m + r * 16) ^ (a_kc & 7)][0] =
                make_uint4(d[0], d[1], d[2], d[3]);
        }
        #pragma unroll
        for (int r = 0; r < 4; ++r) {
            uint32_t d[4];
            #pragma unroll
            for (int p = 0; p < 4; ++p) {
                const uint32_t bv = ((pw[r] >> (4 * p)) & 0x000F000Fu) | 0x64006400u;
                d[p] = __builtin_bit_cast(uint32_t, __builtin_bit_cast(f16x2, bv) - z2);
            }
            *(uint4*)&B_sh[r * 4 + thi][oL][0] = make_uint4(d[0], d[1], d[2], d[3]);
        }

        __syncthreads();

        // ---- issue next tile's loads: latency hides under ds_read+MFMA ----
        issue((t + 1 < NTILES) ? (t + 1) : (NTILES - 1));

        // ---- compute: 4 k-steps of 32, 4 MFMA each ----
        #pragma unroll
        for (int kk = 0; kk < 4; ++kk) {
            const int k8 = kk * 4 + l4;
            f16x8 a[2], b[2];
            #pragma unroll
            for (int i = 0; i < 2; ++i)
                a[i] = *(const f16x8*)&A_sh[k8][(wm * 32 + i * 16 + l15) ^ (k8 & 7)][0];
            #pragma unroll
            for (int j = 0; j < 2; ++j)
                b[j] = *(const f16x8*)&B_sh[k8][wn * 32 + j * 16 + l15][0];
            #pragma unroll
            for (int i = 0; i < 2; ++i)
                #pragma unroll
                for (int j = 0; j < 2; ++j)
                    accg[i][j] = __builtin_amdgcn_mfma_f32_16x16x32_f16(
                                     a[i], b[j], accg[i][j], 0, 0, 0);
        }

        // ---- fold group into running accumulator with per-(g,col) scale ----
        #pragma unroll
        for (int i = 0; i < 2; ++i) {
            #pragma unroll
            for (int r = 0; r < 4; ++r) {
                acc[i][0][r] += sjf0 * accg[i][0][r];
                acc[i][1][r] += sjf1 * accg[i][1][r];
            }
            accg[i][0] = f32x4{0.f, 0.f, 0.f, 0.f};
            accg[i][1] = f32x4{0.f, 0.f, 0.f, 0.f};
        }

        __syncthreads();
    }

    // ---- epilogue: C[row][col] = acc + bias, row=(lane>>4)*4+reg, col=lane&15 ----
    #pragma unroll
    for (int j = 0; j < 2; ++j) {
        const int col = n0 + wn * 32 + j * 16 + l15;
        const float bv = bias[col];
        #pragma unroll
        for (int i = 0; i < 2; ++i) {
            const int row0 = m0 + wm * 32 + i * 16 + l4 * 4;
            #pragma unroll
            for (int r = 0; r < 4; ++r)
                out[(size_t)(row0 + r) * OUTF + col] = acc[i][j][r] + bv;
        }
    }
}

extern "C" void kernel_launch(void* const* d_in, const int* in_sizes, int n_in,
                              void* d_out, int out_size, void* d_ws, size_t ws_size,
                              hipStream_t stream)
{
    const float* x       = (const float*)d_in[0];
    const float* scales  = (const float*)d_in[1];
    const float* bias    = (const float*)d_in[2];
    const int*   qweight = (const int*)d_in[3];
    const int*   qzeros  = (const int*)d_in[4];
    // d_in[5] = g_idx : deterministic (i // 128), not needed on device
    float* out = (float*)d_out;

    dim3 grid(OUTF / BN, NTOK / BM);  // (172, 4) = 688 blocks, ~2.7/CU
    qlin_mfma<<<grid, dim3(256), 0, stream>>>(x, scales, bias, qweight, qzeros, out);
}